// Round 2
// baseline (461.257 us; speedup 1.0000x reference)
//
#include <hip/hip_runtime.h>
#include <hip/hip_bf16.h>

#define FA_EPS 0.1f

// ---------------------------------------------------------------------------
// K0: per-node prep. One wave (64 lanes) per node:
//   al[i] = dot(x[i,:], att_l), ar[i] = dot(x[i,:], att_r)
//   deg[i] = 1  (self-loop)
// ---------------------------------------------------------------------------
__global__ __launch_bounds__(256) void k_node_prep(
    const float* __restrict__ x,
    const float* __restrict__ att_l,
    const float* __restrict__ att_r,
    float* __restrict__ al, float* __restrict__ ar,
    unsigned int* __restrict__ deg, int N)
{
    int wave = (int)((blockIdx.x * blockDim.x + threadIdx.x) >> 6);
    int lane = threadIdx.x & 63;
    if (wave >= N) return;
    const float* xr = x + (size_t)wave * 128;
    float x0 = xr[lane];
    float x1 = xr[lane + 64];
    float pal = x0 * att_l[lane] + x1 * att_l[lane + 64];
    float par = x0 * att_r[lane] + x1 * att_r[lane + 64];
    #pragma unroll
    for (int off = 32; off > 0; off >>= 1) {
        pal += __shfl_down(pal, off);
        par += __shfl_down(par, off);
    }
    if (lane == 0) {
        al[wave] = pal;
        ar[wave] = par;
        deg[wave] = 1u;
    }
}

// ---------------------------------------------------------------------------
// K1: degree count over edges (target = col = edge_index[1])
// ---------------------------------------------------------------------------
__global__ __launch_bounds__(256) void k_degree(
    const int* __restrict__ ei, unsigned int* __restrict__ deg, int E)
{
    int e = (int)(blockIdx.x * blockDim.x + threadIdx.x);
    if (e < E) atomicAdd(&deg[ei[E + e]], 1u);
}

// ---------------------------------------------------------------------------
// K2: dinv[i] = rsqrt(deg[i])   (deg >= 1 always, self-loops)
// ---------------------------------------------------------------------------
__global__ __launch_bounds__(256) void k_dinv(
    const unsigned int* __restrict__ deg, float* __restrict__ dinv, int N)
{
    int i = (int)(blockIdx.x * blockDim.x + threadIdx.x);
    if (i < N) dinv[i] = rsqrtf((float)deg[i]);
}

// ---------------------------------------------------------------------------
// K3: h init = self-loop message + EPS*x:
//   h[i,d] = (tanh(al[i]+ar[i]) * dinv[i]^2 + EPS) * x[i,d]
// ---------------------------------------------------------------------------
__global__ __launch_bounds__(256) void k_hinit(
    const float* __restrict__ x,
    const float* __restrict__ al, const float* __restrict__ ar,
    const float* __restrict__ dinv, float* __restrict__ h, int total)
{
    int idx = (int)(blockIdx.x * blockDim.x + threadIdx.x);
    if (idx >= total) return;
    int i = idx >> 7;
    float di = dinv[i];
    float coef = tanhf(al[i] + ar[i]) * di * di + FA_EPS;
    h[idx] = coef * x[idx];
}

// ---------------------------------------------------------------------------
// K4: edge scatter. One wave per edge:
//   alpha = tanh(al[s] + ar[t]) * dinv[s] * dinv[t]
//   h[t,:] += alpha * x[s,:]    (fp32 atomics, 2 per lane)
// ---------------------------------------------------------------------------
__global__ __launch_bounds__(256) void k_scatter(
    const float* __restrict__ x, const int* __restrict__ ei,
    const float* __restrict__ al, const float* __restrict__ ar,
    const float* __restrict__ dinv, float* __restrict__ h, int E)
{
    int wave = (int)((blockIdx.x * blockDim.x + threadIdx.x) >> 6);
    int lane = threadIdx.x & 63;
    if (wave >= E) return;
    int s = ei[wave];
    int t = ei[E + wave];
    float alpha = tanhf(al[s] + ar[t]) * dinv[s] * dinv[t];
    const float* xr = x + (size_t)s * 128;
    float m0 = alpha * xr[lane];
    float m1 = alpha * xr[lane + 64];
    float* hr = h + (size_t)t * 128;
    atomicAdd(&hr[lane], m0);
    atomicAdd(&hr[lane + 64], m1);
}

// ---------------------------------------------------------------------------
// K5: out = h @ W + bias.  W (128x128 f32) staged in LDS (64 KB); 8 rows per
// block; 256 threads: thread = (rh in 0..1, j in 0..127), rows rh+2m.
// ---------------------------------------------------------------------------
__global__ __launch_bounds__(256) void k_matmul(
    const float* __restrict__ h,
    const float* __restrict__ w,
    const float* __restrict__ bias,
    float* __restrict__ out, int N)
{
    __shared__ float wl[128 * 128];   // 64 KB
    __shared__ float hl[8 * 128];     // 4 KB
    int tid = threadIdx.x;
    for (int k = tid; k < 128 * 128; k += 256) wl[k] = w[k];
    int row0 = (int)blockIdx.x * 8;
    for (int k = tid; k < 8 * 128; k += 256) {
        int r = row0 + (k >> 7);
        hl[k] = (r < N) ? h[(size_t)r * 128 + (k & 127)] : 0.0f;
    }
    __syncthreads();
    int j  = tid & 127;
    int rh = tid >> 7;
    float acc0 = 0.f, acc1 = 0.f, acc2 = 0.f, acc3 = 0.f;
    #pragma unroll 8
    for (int k = 0; k < 128; ++k) {
        float wv = wl[k * 128 + j];
        acc0 += hl[(rh + 0) * 128 + k] * wv;
        acc1 += hl[(rh + 2) * 128 + k] * wv;
        acc2 += hl[(rh + 4) * 128 + k] * wv;
        acc3 += hl[(rh + 6) * 128 + k] * wv;
    }
    float b = bias[j];
    float accs[4] = {acc0, acc1, acc2, acc3};
    #pragma unroll
    for (int m = 0; m < 4; ++m) {
        int r = row0 + rh + 2 * m;
        if (r < N) out[(size_t)r * 128 + j] = accs[m] + b;
    }
}

extern "C" void kernel_launch(void* const* d_in, const int* in_sizes, int n_in,
                              void* d_out, int out_size, void* d_ws, size_t ws_size,
                              hipStream_t stream)
{
    const float* x     = (const float*)d_in[0];
    const int*   ei    = (const int*)d_in[1];
    const float* att_l = (const float*)d_in[2];
    const float* att_r = (const float*)d_in[3];
    const float* w     = (const float*)d_in[4];
    const float* bias  = (const float*)d_in[5];
    float* out = (float*)d_out;

    const int N = in_sizes[0] / 128;   // 50000
    const int E = in_sizes[1] / 2;     // 600000
    const int total = N * 128;

    char* ws = (char*)d_ws;
    float*        h    = (float*)ws;                                 // N*128 f32
    float*        al   = (float*)(ws + (size_t)total * sizeof(float));
    float*        ar   = al + N;
    float*        dinv = ar + N;
    unsigned int* deg  = (unsigned int*)(dinv + N);

    // K0: al/ar dots + deg=1
    {
        int blocks = (N * 64 + 255) / 256;
        k_node_prep<<<blocks, 256, 0, stream>>>(x, att_l, att_r, al, ar, deg, N);
    }
    // K1: degree atomics
    k_degree<<<(E + 255) / 256, 256, 0, stream>>>(ei, deg, E);
    // K2: dinv
    k_dinv<<<(N + 255) / 256, 256, 0, stream>>>(deg, dinv, N);
    // K3: h init (self loop + EPS*x)
    k_hinit<<<(total + 255) / 256, 256, 0, stream>>>(x, al, ar, dinv, h, total);
    // K4: edge scatter (1 wave per edge)
    {
        int blocks = (E * 64 + 255) / 256;   // = E/4 blocks of 4 waves
        k_scatter<<<blocks, 256, 0, stream>>>(x, ei, al, ar, dinv, h, E);
    }
    // K5: matmul + bias -> f32 out
    k_matmul<<<(N + 7) / 8, 256, 0, stream>>>(h, w, bias, out, N);
}

// Round 3
// 260.851 us; speedup vs baseline: 1.7683x; 1.7683x over previous
//
#include <hip/hip_runtime.h>
#include <hip/hip_bf16.h>

#define FA_EPS 0.1f

// ---------------------------------------------------------------------------
// K0: per-node prep. One wave per node:
//   al[i] = dot(x[i,:], att_l), ar[i] = dot(x[i,:], att_r); edeg[i] = 0
// ---------------------------------------------------------------------------
__global__ __launch_bounds__(256) void k_node_prep(
    const float* __restrict__ x,
    const float* __restrict__ att_l,
    const float* __restrict__ att_r,
    float* __restrict__ al, float* __restrict__ ar,
    unsigned int* __restrict__ edeg, int N)
{
    int wave = (int)((blockIdx.x * blockDim.x + threadIdx.x) >> 6);
    int lane = threadIdx.x & 63;
    if (wave >= N) return;
    const float* xr = x + (size_t)wave * 128;
    float x0 = xr[lane];
    float x1 = xr[lane + 64];
    float pal = x0 * att_l[lane] + x1 * att_l[lane + 64];
    float par = x0 * att_r[lane] + x1 * att_r[lane + 64];
    #pragma unroll
    for (int off = 32; off > 0; off >>= 1) {
        pal += __shfl_down(pal, off);
        par += __shfl_down(par, off);
    }
    if (lane == 0) {
        al[wave] = pal;
        ar[wave] = par;
        edeg[wave] = 0u;   // edge-only in-degree (self-loop handled in gather)
    }
}

// ---------------------------------------------------------------------------
// K1: edge in-degree histogram (target = col = edge_index[1])
// ---------------------------------------------------------------------------
__global__ __launch_bounds__(256) void k_degree(
    const int* __restrict__ ei, unsigned int* __restrict__ edeg, int E)
{
    int e = (int)(blockIdx.x * blockDim.x + threadIdx.x);
    if (e < E) atomicAdd(&edeg[ei[E + e]], 1u);
}

// ---------------------------------------------------------------------------
// K2: per-256-chunk reduction of edeg -> partials[b]   (level-1 of scan)
// ---------------------------------------------------------------------------
__global__ __launch_bounds__(256) void k_reduce(
    const unsigned int* __restrict__ edeg, unsigned int* __restrict__ partials,
    int N)
{
    __shared__ unsigned int lds[4];
    int i = (int)(blockIdx.x * blockDim.x + threadIdx.x);
    unsigned int v = (i < N) ? edeg[i] : 0u;
    #pragma unroll
    for (int off = 32; off > 0; off >>= 1) v += __shfl_down(v, off);
    int lane = threadIdx.x & 63, wid = threadIdx.x >> 6;
    if (lane == 0) lds[wid] = v;
    __syncthreads();
    if (threadIdx.x == 0)
        partials[blockIdx.x] = lds[0] + lds[1] + lds[2] + lds[3];
}

// ---------------------------------------------------------------------------
// K3: exclusive scan of partials (single block; NB <= 256 for N <= 65536)
// ---------------------------------------------------------------------------
__global__ __launch_bounds__(256) void k_scan_partials(
    const unsigned int* __restrict__ partials,
    unsigned int* __restrict__ partial_offs, int NB)
{
    __shared__ unsigned int s[256];
    int tid = threadIdx.x;
    unsigned int v = (tid < NB) ? partials[tid] : 0u;
    s[tid] = v;
    __syncthreads();
    #pragma unroll
    for (int off = 1; off < 256; off <<= 1) {
        unsigned int t = (tid >= off) ? s[tid - off] : 0u;
        __syncthreads();
        s[tid] += t;
        __syncthreads();
    }
    partial_offs[tid] = s[tid] - v;   // exclusive
}

// ---------------------------------------------------------------------------
// K4: per-chunk exclusive scan + base -> offs, cursor; dinv = rsqrt(edeg+1)
// ---------------------------------------------------------------------------
__global__ __launch_bounds__(256) void k_chunk_scan(
    const unsigned int* __restrict__ edeg,
    const unsigned int* __restrict__ partial_offs,
    unsigned int* __restrict__ offs, unsigned int* __restrict__ cursor,
    float* __restrict__ dinv, int N)
{
    __shared__ unsigned int s[256];
    int tid = threadIdx.x;
    int i = (int)(blockIdx.x * blockDim.x + tid);
    unsigned int v = (i < N) ? edeg[i] : 0u;
    s[tid] = v;
    __syncthreads();
    #pragma unroll
    for (int off = 1; off < 256; off <<= 1) {
        unsigned int t = (tid >= off) ? s[tid - off] : 0u;
        __syncthreads();
        s[tid] += t;
        __syncthreads();
    }
    if (i < N) {
        unsigned int o = partial_offs[blockIdx.x] + s[tid] - v;
        offs[i] = o;
        cursor[i] = o;
        dinv[i] = rsqrtf((float)(v + 1u));   // +1: self-loop
    }
}

// ---------------------------------------------------------------------------
// K5: bucket fill — counting sort of edges by target; precompute alpha.
// ---------------------------------------------------------------------------
__global__ __launch_bounds__(256) void k_fill(
    const int* __restrict__ ei,
    const float* __restrict__ al, const float* __restrict__ ar,
    const float* __restrict__ dinv,
    unsigned int* __restrict__ cursor,
    int* __restrict__ csr_src, float* __restrict__ csr_alpha, int E)
{
    int e = (int)(blockIdx.x * blockDim.x + threadIdx.x);
    if (e >= E) return;
    int s = ei[e];
    int t = ei[E + e];
    float alpha = tanhf(al[s] + ar[t]) * dinv[s] * dinv[t];
    unsigned int pos = atomicAdd(&cursor[t], 1u);
    csr_src[pos] = s;
    csr_alpha[pos] = alpha;
}

// ---------------------------------------------------------------------------
// K6: gather — one wave per target node; no float atomics.
//   h[t,:] = sum_in alpha*x[s,:] + (tanh(al+ar)*dinv^2 + EPS)*x[t,:]
// ---------------------------------------------------------------------------
__global__ __launch_bounds__(256) void k_gather(
    const float* __restrict__ x,
    const int* __restrict__ csr_src, const float* __restrict__ csr_alpha,
    const unsigned int* __restrict__ offs, const unsigned int* __restrict__ edeg,
    const float* __restrict__ al, const float* __restrict__ ar,
    const float* __restrict__ dinv, float* __restrict__ h, int N)
{
    int t = (int)((blockIdx.x * blockDim.x + threadIdx.x) >> 6);
    int lane = threadIdx.x & 63;
    if (t >= N) return;
    unsigned int beg = offs[t];
    unsigned int cnt = edeg[t];
    float acc0 = 0.f, acc1 = 0.f;
    int s_next = 0; float a_next = 0.f;
    if (cnt > 0) { s_next = csr_src[beg]; a_next = csr_alpha[beg]; }
    for (unsigned int j = 0; j < cnt; ++j) {
        int s = s_next; float a = a_next;
        if (j + 1 < cnt) {                      // 1-deep prefetch of (s, alpha)
            s_next = csr_src[beg + j + 1];
            a_next = csr_alpha[beg + j + 1];
        }
        const float* xr = x + (size_t)s * 128;
        acc0 += a * xr[lane];
        acc1 += a * xr[lane + 64];
    }
    float di = dinv[t];
    float coef = tanhf(al[t] + ar[t]) * di * di + FA_EPS;   // self-loop + EPS
    const float* xt = x + (size_t)t * 128;
    acc0 += coef * xt[lane];
    acc1 += coef * xt[lane + 64];
    h[(size_t)t * 128 + lane] = acc0;
    h[(size_t)t * 128 + 64 + lane] = acc1;
}

// ---------------------------------------------------------------------------
// K7: out = h @ W + bias. 32 rows/block; thread = (rg=tid>>5, jj=(tid&31)*4)
// computes rows rg+8m (m=0..3) x cols jj..jj+3 — 16 FMA per 5 LDS reads.
// LDS: W 64 KB + h-tile 16 KB = 80 KB -> 2 blocks/CU.
// ---------------------------------------------------------------------------
__global__ __launch_bounds__(256) void k_matmul(
    const float* __restrict__ h,
    const float* __restrict__ w,
    const float* __restrict__ bias,
    float* __restrict__ out, int N)
{
    __shared__ float wl[128 * 128];   // 64 KB
    __shared__ float hl[32 * 128];    // 16 KB
    int tid = threadIdx.x;
    for (int k = tid; k < 128 * 128; k += 256) wl[k] = w[k];
    int row0 = (int)blockIdx.x * 32;
    for (int k = tid; k < 32 * 128; k += 256) {
        int r = row0 + (k >> 7);
        hl[k] = (r < N) ? h[(size_t)r * 128 + (k & 127)] : 0.0f;
    }
    __syncthreads();
    int jj = (tid & 31) * 4;
    int rg = tid >> 5;                // 0..7
    float4 acc[4];
    #pragma unroll
    for (int m = 0; m < 4; ++m) acc[m] = make_float4(0.f, 0.f, 0.f, 0.f);
    #pragma unroll 4
    for (int k = 0; k < 128; ++k) {
        float4 w4 = *(const float4*)&wl[k * 128 + jj];
        float h0 = hl[(rg +  0) * 128 + k];
        float h1 = hl[(rg +  8) * 128 + k];
        float h2 = hl[(rg + 16) * 128 + k];
        float h3 = hl[(rg + 24) * 128 + k];
        acc[0].x += h0 * w4.x; acc[0].y += h0 * w4.y; acc[0].z += h0 * w4.z; acc[0].w += h0 * w4.w;
        acc[1].x += h1 * w4.x; acc[1].y += h1 * w4.y; acc[1].z += h1 * w4.z; acc[1].w += h1 * w4.w;
        acc[2].x += h2 * w4.x; acc[2].y += h2 * w4.y; acc[2].z += h2 * w4.z; acc[2].w += h2 * w4.w;
        acc[3].x += h3 * w4.x; acc[3].y += h3 * w4.y; acc[3].z += h3 * w4.z; acc[3].w += h3 * w4.w;
    }
    float4 b4 = *(const float4*)&bias[jj];
    #pragma unroll
    for (int m = 0; m < 4; ++m) {
        int r = row0 + rg + 8 * m;
        if (r < N) {
            float4 o;
            o.x = acc[m].x + b4.x; o.y = acc[m].y + b4.y;
            o.z = acc[m].z + b4.z; o.w = acc[m].w + b4.w;
            *(float4*)&out[(size_t)r * 128 + jj] = o;
        }
    }
}

extern "C" void kernel_launch(void* const* d_in, const int* in_sizes, int n_in,
                              void* d_out, int out_size, void* d_ws, size_t ws_size,
                              hipStream_t stream)
{
    const float* x     = (const float*)d_in[0];
    const int*   ei    = (const int*)d_in[1];
    const float* att_l = (const float*)d_in[2];
    const float* att_r = (const float*)d_in[3];
    const float* w     = (const float*)d_in[4];
    const float* bias  = (const float*)d_in[5];
    float* out = (float*)d_out;

    const int N = in_sizes[0] / 128;   // 50000
    const int E = in_sizes[1] / 2;     // 600000
    const int NB = (N + 255) / 256;    // 196 (must be <= 256)

    char* ws = (char*)d_ws;
    float*        h            = (float*)ws;                      // N*128
    float*        al           = h + (size_t)N * 128;             // N
    float*        ar           = al + N;                          // N
    float*        dinv         = ar + N;                          // N
    unsigned int* edeg         = (unsigned int*)(dinv + N);       // N
    unsigned int* offs         = edeg + N;                        // N
    unsigned int* cursor       = offs + N;                        // N
    unsigned int* partials     = cursor + N;                      // 256
    unsigned int* partial_offs = partials + 256;                  // 256
    int*          csr_src      = (int*)(partial_offs + 256);      // E
    float*        csr_alpha    = (float*)(csr_src + E);           // E

    // K0: al/ar dots, edeg=0
    k_node_prep<<<(N * 64 + 255) / 256, 256, 0, stream>>>(x, att_l, att_r, al, ar, edeg, N);
    // K1: edge in-degree
    k_degree<<<(E + 255) / 256, 256, 0, stream>>>(ei, edeg, E);
    // K2-K4: two-level exclusive scan -> offs/cursor; dinv
    k_reduce<<<NB, 256, 0, stream>>>(edeg, partials, N);
    k_scan_partials<<<1, 256, 0, stream>>>(partials, partial_offs, NB);
    k_chunk_scan<<<NB, 256, 0, stream>>>(edeg, partial_offs, offs, cursor, dinv, N);
    // K5: counting-sort fill with precomputed alpha
    k_fill<<<(E + 255) / 256, 256, 0, stream>>>(ei, al, ar, dinv, cursor, csr_src, csr_alpha, E);
    // K6: gather (1 wave per target, no float atomics), folds self-loop + EPS
    k_gather<<<(N * 64 + 255) / 256, 256, 0, stream>>>(x, csr_src, csr_alpha, offs, edeg,
                                                       al, ar, dinv, h, N);
    // K7: matmul + bias
    k_matmul<<<(N + 31) / 32, 256, 0, stream>>>(h, w, bias, out, N);
}

// Round 4
// 217.326 us; speedup vs baseline: 2.1224x; 1.2003x over previous
//
#include <hip/hip_runtime.h>
#include <hip/hip_bf16.h>

#define FA_EPS 0.1f

typedef _Float16 half8  __attribute__((ext_vector_type(8)));
typedef _Float16 half2v __attribute__((ext_vector_type(2)));
typedef float    f32x4  __attribute__((ext_vector_type(4)));

// ---------------------------------------------------------------------------
// K0: per-node prep. One wave per node (float2 lanes: cols 2l,2l+1):
//   al[i] = dot(x[i,:], att_l), ar[i] = dot(x[i,:], att_r); edeg[i] = 0
// ---------------------------------------------------------------------------
__global__ __launch_bounds__(256) void k_node_prep(
    const float* __restrict__ x,
    const float* __restrict__ att_l,
    const float* __restrict__ att_r,
    float* __restrict__ al, float* __restrict__ ar,
    unsigned int* __restrict__ edeg, int N)
{
    int node = (int)((blockIdx.x * blockDim.x + threadIdx.x) >> 6);
    int lane = threadIdx.x & 63;
    if (node >= N) return;
    const float2* xr = (const float2*)(x + (size_t)node * 128);
    float2 v  = xr[lane];
    float2 l2 = ((const float2*)att_l)[lane];
    float2 r2 = ((const float2*)att_r)[lane];
    float pal = v.x * l2.x + v.y * l2.y;
    float par = v.x * r2.x + v.y * r2.y;
    #pragma unroll
    for (int off = 32; off > 0; off >>= 1) {
        pal += __shfl_down(pal, off);
        par += __shfl_down(par, off);
    }
    if (lane == 0) {
        al[node] = pal;
        ar[node] = par;
        edeg[node] = 0u;
    }
}

// ---------------------------------------------------------------------------
// K1: edge in-degree histogram (target = col = edge_index[1])
// ---------------------------------------------------------------------------
__global__ __launch_bounds__(256) void k_degree(
    const int* __restrict__ ei, unsigned int* __restrict__ edeg, int E)
{
    int e = (int)(blockIdx.x * blockDim.x + threadIdx.x);
    if (e < E) atomicAdd(&edeg[ei[E + e]], 1u);
}

// ---------------------------------------------------------------------------
// K2: per-256-chunk reduction of edeg -> partials[b]
// ---------------------------------------------------------------------------
__global__ __launch_bounds__(256) void k_reduce(
    const unsigned int* __restrict__ edeg, unsigned int* __restrict__ partials,
    int N)
{
    __shared__ unsigned int lds[4];
    int i = (int)(blockIdx.x * blockDim.x + threadIdx.x);
    unsigned int v = (i < N) ? edeg[i] : 0u;
    #pragma unroll
    for (int off = 32; off > 0; off >>= 1) v += __shfl_down(v, off);
    int lane = threadIdx.x & 63, wid = threadIdx.x >> 6;
    if (lane == 0) lds[wid] = v;
    __syncthreads();
    if (threadIdx.x == 0)
        partials[blockIdx.x] = lds[0] + lds[1] + lds[2] + lds[3];
}

// ---------------------------------------------------------------------------
// K3: exclusive scan of partials (single block; NB <= 256)
// ---------------------------------------------------------------------------
__global__ __launch_bounds__(256) void k_scan_partials(
    const unsigned int* __restrict__ partials,
    unsigned int* __restrict__ partial_offs, int NB)
{
    __shared__ unsigned int s[256];
    int tid = threadIdx.x;
    unsigned int v = (tid < NB) ? partials[tid] : 0u;
    s[tid] = v;
    __syncthreads();
    #pragma unroll
    for (int off = 1; off < 256; off <<= 1) {
        unsigned int t = (tid >= off) ? s[tid - off] : 0u;
        __syncthreads();
        s[tid] += t;
        __syncthreads();
    }
    partial_offs[tid] = s[tid] - v;
}

// ---------------------------------------------------------------------------
// K4: per-chunk exclusive scan + base -> offs, cursor; dinv = rsqrt(edeg+1)
// ---------------------------------------------------------------------------
__global__ __launch_bounds__(256) void k_chunk_scan(
    const unsigned int* __restrict__ edeg,
    const unsigned int* __restrict__ partial_offs,
    unsigned int* __restrict__ offs, unsigned int* __restrict__ cursor,
    float* __restrict__ dinv, int N)
{
    __shared__ unsigned int s[256];
    int tid = threadIdx.x;
    int i = (int)(blockIdx.x * blockDim.x + tid);
    unsigned int v = (i < N) ? edeg[i] : 0u;
    s[tid] = v;
    __syncthreads();
    #pragma unroll
    for (int off = 1; off < 256; off <<= 1) {
        unsigned int t = (tid >= off) ? s[tid - off] : 0u;
        __syncthreads();
        s[tid] += t;
        __syncthreads();
    }
    if (i < N) {
        unsigned int o = partial_offs[blockIdx.x] + s[tid] - v;
        offs[i] = o;
        cursor[i] = o;
        dinv[i] = rsqrtf((float)(v + 1u));   // +1: self-loop
    }
}

// ---------------------------------------------------------------------------
// K5: bucket fill — counting sort of edges by target; csr = int2{src, alpha}
// ---------------------------------------------------------------------------
__global__ __launch_bounds__(256) void k_fill(
    const int* __restrict__ ei,
    const float* __restrict__ al, const float* __restrict__ ar,
    const float* __restrict__ dinv,
    unsigned int* __restrict__ cursor,
    int2* __restrict__ csr, int E)
{
    int e = (int)(blockIdx.x * blockDim.x + threadIdx.x);
    if (e >= E) return;
    int s = ei[e];
    int t = ei[E + e];
    float alpha = tanhf(al[s] + ar[t]) * dinv[s] * dinv[t];
    unsigned int pos = atomicAdd(&cursor[t], 1u);
    csr[pos] = make_int2(s, __float_as_int(alpha));
}

// ---------------------------------------------------------------------------
// K6: gather — one wave per target; float2 x-loads, int2 csr, unroll-4 MLP.
//   h16[t,:] = (f16) [ sum_in alpha*x[s,:] + (tanh(al+ar)*dinv^2+EPS)*x[t,:] ]
// ---------------------------------------------------------------------------
__global__ __launch_bounds__(256) void k_gather(
    const float* __restrict__ x,
    const int2* __restrict__ csr,
    const unsigned int* __restrict__ offs, const unsigned int* __restrict__ edeg,
    const float* __restrict__ al, const float* __restrict__ ar,
    const float* __restrict__ dinv, _Float16* __restrict__ h16, int N)
{
    int t = (int)((blockIdx.x * blockDim.x + threadIdx.x) >> 6);
    int lane = threadIdx.x & 63;
    if (t >= N) return;
    const float2* x2 = (const float2*)x;       // row stride 64 float2
    const int2* cs = csr + offs[t];
    unsigned int cnt = edeg[t];
    float acc0 = 0.f, acc1 = 0.f;
    unsigned int j = 0;
    for (; j + 4 <= cnt; j += 4) {
        int2 e0 = cs[j + 0];
        int2 e1 = cs[j + 1];
        int2 e2 = cs[j + 2];
        int2 e3 = cs[j + 3];
        float2 v0 = x2[(size_t)e0.x * 64 + lane];
        float2 v1 = x2[(size_t)e1.x * 64 + lane];
        float2 v2 = x2[(size_t)e2.x * 64 + lane];
        float2 v3 = x2[(size_t)e3.x * 64 + lane];
        float a0 = __int_as_float(e0.y), a1 = __int_as_float(e1.y);
        float a2 = __int_as_float(e2.y), a3 = __int_as_float(e3.y);
        acc0 += a0 * v0.x + a1 * v1.x + a2 * v2.x + a3 * v3.x;
        acc1 += a0 * v0.y + a1 * v1.y + a2 * v2.y + a3 * v3.y;
    }
    for (; j < cnt; ++j) {
        int2 e = cs[j];
        float2 v = x2[(size_t)e.x * 64 + lane];
        float a = __int_as_float(e.y);
        acc0 += a * v.x;
        acc1 += a * v.y;
    }
    float di = dinv[t];
    float coef = tanhf(al[t] + ar[t]) * di * di + FA_EPS;   // self-loop + EPS
    float2 vt = x2[(size_t)t * 64 + lane];
    acc0 += coef * vt.x;
    acc1 += coef * vt.y;
    half2v hv;
    hv[0] = (_Float16)acc0;
    hv[1] = (_Float16)acc1;
    *((half2v*)(h16 + (size_t)t * 128) + lane) = hv;
}

// ---------------------------------------------------------------------------
// K7: W (f32 [k][n]) -> Wt (f16 [n][k])   (16384 elems)
// ---------------------------------------------------------------------------
__global__ __launch_bounds__(256) void k_wconv(
    const float* __restrict__ w, _Float16* __restrict__ wt)
{
    int i = (int)(blockIdx.x * blockDim.x + threadIdx.x);
    int k = i >> 7, n = i & 127;
    wt[n * 128 + k] = (_Float16)w[k * 128 + n];
}

// ---------------------------------------------------------------------------
// K8: out = h16 @ W + bias via mfma_f32_16x16x32_f16.
// Block = 4 waves, 64 rows. Wt staged in LDS with +8 half row pad
// (row stride 136 halfs -> worst 2-way bank conflict = free).
// A-frag: lane holds h16[r0 + (lane&15)][k0 + (lane>>4)*8 + 0..7]  (16B).
// B-frag: lane holds Wt[n0 + (lane&15)][k0 + (lane>>4)*8 + 0..7]   (16B LDS).
// D: col = lane&15, row = (lane>>4)*4 + reg.
// ---------------------------------------------------------------------------
__global__ __launch_bounds__(256) void k_matmul_mfma(
    const _Float16* __restrict__ h16,
    const _Float16* __restrict__ wt,
    const float* __restrict__ bias,
    float* __restrict__ out, int N)
{
    __shared__ _Float16 wl[128 * 136];   // padded rows, 34 KB
    int tid = threadIdx.x;
    {   // stage Wt as f32 pairs: row r = i>>6, dword-in-row = i&63
        const float* wsrc = (const float*)wt;
        float* wdst = (float*)wl;
        #pragma unroll
        for (int i = tid; i < 8192; i += 256)
            wdst[(i >> 6) * 68 + (i & 63)] = wsrc[i];
    }
    __syncthreads();
    int wv   = tid >> 6;
    int lane = tid & 63;
    int m    = lane & 15;
    int quad = lane >> 4;
    int r0 = (int)blockIdx.x * 64 + wv * 16;
    f32x4 acc[8];
    #pragma unroll
    for (int t = 0; t < 8; ++t) acc[t] = (f32x4)0.f;
    const _Float16* arow = h16 + (size_t)(r0 + m) * 128 + quad * 8;
    #pragma unroll
    for (int k0 = 0; k0 < 128; k0 += 32) {
        half8 a = *(const half8*)(arow + k0);
        #pragma unroll
        for (int t = 0; t < 8; ++t) {
            const _Float16* bp = wl + (size_t)(t * 16 + m) * 136 + quad * 8 + k0;
            half8 b = *(const half8*)bp;
            acc[t] = __builtin_amdgcn_mfma_f32_16x16x32_f16(a, b, acc[t], 0, 0, 0);
        }
    }
    int orow = r0 + quad * 4;
    #pragma unroll
    for (int t = 0; t < 8; ++t) {
        int col = t * 16 + m;
        float bc = bias[col];
        #pragma unroll
        for (int rg = 0; rg < 4; ++rg) {
            int r = orow + rg;
            if (r < N) out[(size_t)r * 128 + col] = acc[t][rg] + bc;
        }
    }
}

extern "C" void kernel_launch(void* const* d_in, const int* in_sizes, int n_in,
                              void* d_out, int out_size, void* d_ws, size_t ws_size,
                              hipStream_t stream)
{
    const float* x     = (const float*)d_in[0];
    const int*   ei    = (const int*)d_in[1];
    const float* att_l = (const float*)d_in[2];
    const float* att_r = (const float*)d_in[3];
    const float* w     = (const float*)d_in[4];
    const float* bias  = (const float*)d_in[5];
    float* out = (float*)d_out;

    const int N  = in_sizes[0] / 128;     // 50000
    const int E  = in_sizes[1] / 2;       // 600000
    const int NB = (N + 255) / 256;       // 196 (<= 256)
    const int NP = ((N + 63) / 64) * 64;  // 50048 rows (pad for MFMA tiles)

    char* ws = (char*)d_ws;
    _Float16*     h16          = (_Float16*)ws;                       // NP*128 f16
    float*        al           = (float*)(ws + (size_t)NP * 128 * 2); // N
    float*        ar           = al + N;
    float*        dinv         = ar + N;
    unsigned int* edeg         = (unsigned int*)(dinv + N);
    unsigned int* offs         = edeg + N;
    unsigned int* cursor       = offs + N;
    unsigned int* partials     = cursor + N;                          // 256
    unsigned int* partial_offs = partials + 256;                      // 256
    int2*         csr          = (int2*)(partial_offs + 256);         // E
    _Float16*     wt           = (_Float16*)(csr + E);                // 16384

    k_node_prep<<<(N * 64 + 255) / 256, 256, 0, stream>>>(x, att_l, att_r, al, ar, edeg, N);
    k_degree<<<(E + 255) / 256, 256, 0, stream>>>(ei, edeg, E);
    k_reduce<<<NB, 256, 0, stream>>>(edeg, partials, N);
    k_scan_partials<<<1, 256, 0, stream>>>(partials, partial_offs, NB);
    k_chunk_scan<<<NB, 256, 0, stream>>>(edeg, partial_offs, offs, cursor, dinv, N);
    k_fill<<<(E + 255) / 256, 256, 0, stream>>>(ei, al, ar, dinv, cursor, csr, E);
    k_gather<<<(N * 64 + 255) / 256, 256, 0, stream>>>(x, csr, offs, edeg, al, ar, dinv, h16, N);
    k_wconv<<<64, 256, 0, stream>>>(w, wt);
    k_matmul_mfma<<<NP / 64, 256, 0, stream>>>(h16, wt, bias, out, N);
}